// Round 1
// baseline (993.925 us; speedup 1.0000x reference)
//
#include <hip/hip_runtime.h>

typedef __attribute__((ext_vector_type(8))) short short8;
typedef __attribute__((ext_vector_type(4))) float f32x4;

#define BB 32
#define LL 2048
#define HH 256
#define MTOT (BB*LL)          // 65536 rows
#define KK 1536               // 6 chunks * 256
#define HSIZE (MTOT*HH)       // 16777216 elements per output tensor

__device__ __forceinline__ unsigned short f2bf(float f){
    unsigned u = __builtin_bit_cast(unsigned, f);
    u += 0x7FFFu + ((u >> 16) & 1u);          // round-to-nearest-even
    return (unsigned short)(u >> 16);
}
__device__ __forceinline__ unsigned pk2(float lo, float hi){
    return (unsigned)f2bf(lo) | ((unsigned)f2bf(hi) << 16);
}
__device__ __forceinline__ float sigm(float v){
    return 1.0f / (1.0f + __expf(-v));
}
__device__ __forceinline__ float ftanh(float v){
    v = fminf(fmaxf(v, -30.0f), 30.0f);
    float e = __expf(2.0f * v);
    return (e - 1.0f) / (e + 1.0f);
}

// ---------------------------------------------------------------------------
// Ws [6][1536][256] f32  ->  Bt [1536][1536] bf16, Bt[g*256+h][k] = Ws[g][k][h]
// 64x64 LDS tile transpose; both global sides coalesced.
// ---------------------------------------------------------------------------
__global__ __launch_bounds__(256) void prep_bt(const float* __restrict__ Ws,
                                               unsigned short* __restrict__ Bt){
    __shared__ float tile[64][65];
    int bid = blockIdx.x;
    int kb = bid % 24; int tmp = bid / 24; int hb = tmp & 3; int g = tmp >> 2;
    int t = threadIdx.x;
    const float* src = Ws + (size_t)g * (KK * HH) + (size_t)(kb * 64) * HH + hb * 64;
    #pragma unroll
    for (int it = 0; it < 16; ++it){
        int e = it * 256 + t; int kk = e >> 6, hh = e & 63;
        tile[kk][hh] = src[(size_t)kk * HH + hh];
    }
    __syncthreads();
    unsigned short* dst = Bt + (size_t)(g * 256 + hb * 64) * KK + kb * 64;
    #pragma unroll
    for (int it = 0; it < 16; ++it){
        int e = it * 256 + t; int hh = e >> 6, kk = e & 63;
        dst[(size_t)hh * KK + kk] = f2bf(tile[kk][hh]);
    }
}

// ---------------------------------------------------------------------------
// Fused GEMM (bf16 MFMA) + sLSTM epilogue.
// Block tile: 128 rows x (6 gates x 64 h). 8 waves: wave = 64 rows x (6g x 16h).
// K = 1536 staged in BK=32 steps; chunk c = k>>8 selects source tensor/shift.
// ---------------------------------------------------------------------------
__global__ __launch_bounds__(512, 2) void slstm_fused(
    const float* __restrict__ h_t, const float* __restrict__ x,
    const float* __restrict__ h_slot, const float* __restrict__ h_intent,
    const float* __restrict__ c_t, const float* __restrict__ bs,
    const unsigned short* __restrict__ Bt, float* __restrict__ out)
{
    __shared__ unsigned short As[128 * 40];   // 128 rows x BK32, pad->40 (80B stride)
    __shared__ unsigned short Bs[384 * 40];   // 384 cols x BK32, pad->40

    const int t    = threadIdx.x;
    const int wv   = t >> 6,  ln  = t & 63;
    const int rg   = wv >> 2, ht  = wv & 3;    // row-group (0/1), h-tile (0..3)
    const int quad = ln >> 4, l16 = ln & 15;

    const int h_chunk = blockIdx.x & 3;        // h fastest -> L3 reuse of A rows
    const int m_block = blockIdx.x >> 2;
    const int h0      = h_chunk * 64;

    // A-staging coords: thread -> (row 0..127, 8 consecutive k)
    const int  arow = t >> 2;
    const int  akq  = (t & 3) << 3;            // 0,8,16,24
    const long mg   = (long)m_block * 128 + arow;
    const int  lseq = (int)(mg & (LL - 1));

    f32x4 acc[4][6] = {};                      // [m-tile][gate], 96 VGPRs

    for (int ks = 0; ks < 48; ++ks){
        // ---- stage A tile (f32 -> bf16, shift-aware gather) ----
        {
            int c  = ks >> 3;                  // which of the 6 cat chunks
            int kk = ((ks & 7) << 5) + akq;    // offset within chunk [0,256)
            const float* src; int sh;
            switch (c){
                case 0:  src = h_t;      sh =  0; break;
                case 1:  src = h_t;      sh = -1; break;   // h_left
                case 2:  src = h_t;      sh =  1; break;   // h_right
                case 3:  src = x;        sh =  0; break;
                case 4:  src = h_slot;   sh =  0; break;
                default: src = h_intent; sh =  0; break;
            }
            int sl = lseq + sh;
            float4 v0 = make_float4(0.f,0.f,0.f,0.f), v1 = v0;
            if ((unsigned)sl < (unsigned)LL){
                const float* p = src + ((mg + sh) * HH + kk);
                v0 = *(const float4*)p;
                v1 = *(const float4*)(p + 4);
            }
            uint4 w;
            w.x = pk2(v0.x, v0.y); w.y = pk2(v0.z, v0.w);
            w.z = pk2(v1.x, v1.y); w.w = pk2(v1.z, v1.w);
            *(uint4*)&As[arow * 40 + akq] = w;
        }
        // ---- stage B tile (bf16 passthrough from Bt) ----
        #pragma unroll
        for (int i = 0; i < 3; ++i){
            int s   = i * 512 + t;
            int col = s >> 2;                  // 0..383
            int kq  = (s & 3) << 3;
            int g   = col >> 6, hc = col & 63;
            const uint4 bv = *(const uint4*)(Bt + (size_t)(g * 256 + h0 + hc) * KK + ks * 32 + kq);
            *(uint4*)&Bs[col * 40 + kq] = bv;
        }
        __syncthreads();
        // ---- fragments + MFMA ----
        short8 a[4];
        #pragma unroll
        for (int mt = 0; mt < 4; ++mt)
            a[mt] = *(const short8*)&As[(rg * 64 + mt * 16 + l16) * 40 + quad * 8];
        #pragma unroll
        for (int g = 0; g < 6; ++g){
            short8 bfrag = *(const short8*)&Bs[(g * 64 + ht * 16 + l16) * 40 + quad * 8];
            #pragma unroll
            for (int mt = 0; mt < 4; ++mt)
                acc[mt][g] = __builtin_amdgcn_mfma_f32_16x16x32_bf16(a[mt], bfrag, acc[mt][g], 0, 0, 0);
        }
        __syncthreads();
    }

    // ---- epilogue: all 6 gates for (row,h) live in this lane ----
    const int h = h0 + ht * 16 + l16;
    float bias[6];
    #pragma unroll
    for (int g = 0; g < 6; ++g) bias[g] = bs[g * HH + h];

    #pragma unroll
    for (int mt = 0; mt < 4; ++mt){
        #pragma unroll
        for (int r = 0; r < 4; ++r){
            long row = (long)m_block * 128 + rg * 64 + mt * 16 + quad * 4 + r;
            int  ls  = (int)(row & (LL - 1));
            float gi = sigm(acc[mt][0][r] + bias[0]);
            float go = sigm(acc[mt][1][r] + bias[1]);
            float gf = sigm(acc[mt][2][r] + bias[2]);
            float gl = sigm(acc[mt][3][r] + bias[3]);
            float gr = sigm(acc[mt][4][r] + bias[4]);
            float gu = ftanh(acc[mt][5][r] + bias[5]);
            // softmax over the sigmoid outputs [i, f, l, r]
            float ei = __expf(gi), ef = __expf(gf), el = __expf(gl), er = __expf(gr);
            float inv = 1.0f / (ei + ef + el + er);
            float cm  = c_t[row * HH + h];
            float clv = (ls > 0)      ? c_t[(row - 1) * HH + h] : 0.0f;
            float crv = (ls < LL - 1) ? c_t[(row + 1) * HH + h] : 0.0f;
            float cn  = (ef * cm + el * clv + er * crv + ei * gu) * inv;
            float hn  = go * ftanh(cn);
            out[row * HH + h]         = hn;
            out[HSIZE + row * HH + h] = cn;
        }
    }
}

extern "C" void kernel_launch(void* const* d_in, const int* in_sizes, int n_in,
                              void* d_out, int out_size, void* d_ws, size_t ws_size,
                              hipStream_t stream){
    const float* h_t      = (const float*)d_in[0];
    const float* x        = (const float*)d_in[1];
    const float* h_slot   = (const float*)d_in[2];
    const float* h_intent = (const float*)d_in[3];
    const float* c_t      = (const float*)d_in[4];
    const float* Ws       = (const float*)d_in[5];
    const float* bs       = (const float*)d_in[6];
    unsigned short* Bt    = (unsigned short*)d_ws;   // 1536*1536 bf16 = 4.7 MB

    prep_bt<<<576, 256, 0, stream>>>(Ws, Bt);
    slstm_fused<<<2048, 512, 0, stream>>>(h_t, x, h_slot, h_intent, c_t, bs, Bt, (float*)d_out);
}